// Round 1
// baseline (4995.763 us; speedup 1.0000x reference)
//
#include <hip/hip_runtime.h>
#include <math.h>

#define C_DIM 1280
#define T_DIM 1024
#define NIMG 5
#define HEADS 20
#define HD 64
#define NSEL 512
#define MROWS (10 * T_DIM)   // 10240
#define SCTX (4 * NSEL + T_DIM) // 3072

// ---------------------------------------------------------------------------
// Kernel 1: fused QKV projection GEMM.
// X (10240 x 1280) @ {Wq|Wk|Wv} (1280 x 1280) -> Q/K/V in [n][h][t][d] layout.
// grid = (30, 80): blockIdx.x selects (which W, 128-col block), y = 128-row blk
// ---------------------------------------------------------------------------
__global__ __launch_bounds__(256) void qkv_gemm(
    const float* __restrict__ X, const float* __restrict__ Wq,
    const float* __restrict__ Wk, const float* __restrict__ Wv,
    float* __restrict__ Qo, float* __restrict__ Ko, float* __restrict__ Vo)
{
    __shared__ float As[16][132];  // [k][m], padded stride 132 -> 2-way max
    __shared__ float Bs[16][132];  // [k][n]
    const int tid = threadIdx.x;
    const int tx = tid & 15, ty = tid >> 4;
    const int bn = blockIdx.x;
    const int bm = blockIdx.y;
    const int wsel = bn / 10;
    const int cW = (bn - wsel * 10) * 128;
    const float* __restrict__ W = (wsel == 0) ? Wq : (wsel == 1) ? Wk : Wv;
    float* __restrict__ Out = (wsel == 0) ? Qo : (wsel == 1) ? Ko : Vo;
    const int r0 = bm * 128;

    float acc[2][2][4][4];
    #pragma unroll
    for (int a = 0; a < 2; a++)
        #pragma unroll
        for (int b = 0; b < 2; b++)
            #pragma unroll
            for (int i = 0; i < 4; i++)
                #pragma unroll
                for (int j = 0; j < 4; j++) acc[a][b][i][j] = 0.f;

    for (int kk = 0; kk < C_DIM; kk += 16) {
        // A tile: 128 rows x 16 cols, store transposed [k][m]
        #pragma unroll
        for (int rep = 0; rep < 2; rep++) {
            int flat = rep * 256 + tid;
            int row = flat >> 2, ch = flat & 3;
            float4 v = *(const float4*)(X + (size_t)(r0 + row) * C_DIM + kk + ch * 4);
            As[ch * 4 + 0][row] = v.x;
            As[ch * 4 + 1][row] = v.y;
            As[ch * 4 + 2][row] = v.z;
            As[ch * 4 + 3][row] = v.w;
        }
        // B tile: 16 rows x 128 cols, natural
        #pragma unroll
        for (int rep = 0; rep < 2; rep++) {
            int flat = rep * 256 + tid;
            int row = flat >> 5, ch = flat & 31;
            *(float4*)&Bs[row][ch * 4] =
                *(const float4*)(W + (size_t)(kk + row) * C_DIM + cW + ch * 4);
        }
        __syncthreads();
        #pragma unroll
        for (int k = 0; k < 16; k++) {
            float4 a0 = *(float4*)&As[k][ty * 4];
            float4 a1 = *(float4*)&As[k][64 + ty * 4];
            float4 b0 = *(float4*)&Bs[k][tx * 4];
            float4 b1 = *(float4*)&Bs[k][64 + tx * 4];
            float av[2][4] = {{a0.x, a0.y, a0.z, a0.w}, {a1.x, a1.y, a1.z, a1.w}};
            float bv[2][4] = {{b0.x, b0.y, b0.z, b0.w}, {b1.x, b1.y, b1.z, b1.w}};
            #pragma unroll
            for (int p = 0; p < 2; p++)
                #pragma unroll
                for (int q = 0; q < 4; q++)
                    #pragma unroll
                    for (int u = 0; u < 2; u++)
                        #pragma unroll
                        for (int w = 0; w < 4; w++)
                            acc[p][u][q][w] += av[p][q] * bv[u][w];
        }
        __syncthreads();
    }
    // scatter epilogue into [n][h][t][d]
    #pragma unroll
    for (int rb = 0; rb < 2; rb++)
        #pragma unroll
        for (int rr = 0; rr < 4; rr++) {
            int r = r0 + rb * 64 + ty * 4 + rr;
            int n = r >> 10, t = r & 1023;
            #pragma unroll
            for (int cb = 0; cb < 2; cb++) {
                int c = cW + cb * 64 + tx * 4;
                int h = c >> 6, d = c & 63;
                float4 v = make_float4(acc[rb][cb][rr][0], acc[rb][cb][rr][1],
                                       acc[rb][cb][rr][2], acc[rb][cb][rr][3]);
                *(float4*)(Out + ((size_t)((n * HEADS + h) * T_DIM + t)) * HD + d) = v;
            }
        }
}

// ---------------------------------------------------------------------------
// Kernel 2: flash attention, f32, one block per (qtile=64, head, n).
// ctx row map: r<2048 -> (j=jl[r>>9], t=idx[j][r&511]); else (j=i, t=r-2048)
// ---------------------------------------------------------------------------
__global__ __launch_bounds__(256) void flash_attn(
    const float* __restrict__ Qg, const float* __restrict__ Kg,
    const float* __restrict__ Vg, const int* __restrict__ idx,
    float* __restrict__ Og)
{
    __shared__ float Qs[64][64];  // [d][r]  (write conflicts once per block: ok)
    __shared__ float Ks[64][65];  // [d][k]  padded (transposed writes per tile)
    __shared__ float Vs[64][64];  // [k][d]  natural
    __shared__ float Ps[64][65];  // [k][r]  padded
    const int tid = threadIdx.x;
    const int tx = tid & 15, ty = tid >> 4;
    const int qt = blockIdx.x, h = blockIdx.y, n = blockIdx.z;
    const int b = n / NIMG, i = n - b * NIMG;
    int jl[4];
    { int c = 0; for (int j = 0; j < NIMG; j++) if (j != i) jl[c++] = j; }

    const size_t qbase = ((size_t)(n * HEADS + h)) * T_DIM * HD;
    const float scale = 0.125f;  // 1/sqrt(64)
    #pragma unroll
    for (int rep = 0; rep < 4; rep++) {
        int flat = rep * 256 + tid;
        int rr = flat >> 4, ch = flat & 15;
        float4 v = *(const float4*)(Qg + qbase + (size_t)(qt * 64 + rr) * HD + ch * 4);
        Qs[ch * 4 + 0][rr] = v.x * scale;
        Qs[ch * 4 + 1][rr] = v.y * scale;
        Qs[ch * 4 + 2][rr] = v.z * scale;
        Qs[ch * 4 + 3][rr] = v.w * scale;
    }

    float m[4], l[4], acc[4][4];
    #pragma unroll
    for (int r = 0; r < 4; r++) {
        m[r] = -INFINITY; l[r] = 0.f;
        #pragma unroll
        for (int c = 0; c < 4; c++) acc[r][c] = 0.f;
    }

    for (int kt = 0; kt < SCTX / 64; kt++) {
        __syncthreads();  // prev PV readers of Ks/Vs/Ps done
        // gather K,V tile (64 ctx rows x 64 d)
        #pragma unroll
        for (int rep = 0; rep < 4; rep++) {
            int flat = rep * 256 + tid;
            int kk = flat >> 4, ch = flat & 15;
            int cr = kt * 64 + kk;
            int j, st;
            if (cr < 4 * NSEL) { j = jl[cr >> 9]; st = idx[j * NSEL + (cr & (NSEL - 1))]; }
            else               { j = i;           st = cr - 4 * NSEL; }
            const size_t base = ((size_t)((b * NIMG + j) * HEADS + h) * T_DIM + st) * HD;
            float4 kv = *(const float4*)(Kg + base + ch * 4);
            Ks[ch * 4 + 0][kk] = kv.x;
            Ks[ch * 4 + 1][kk] = kv.y;
            Ks[ch * 4 + 2][kk] = kv.z;
            Ks[ch * 4 + 3][kk] = kv.w;
            float4 vv = *(const float4*)(Vg + base + ch * 4);
            *(float4*)&Vs[kk][ch * 4] = vv;
        }
        __syncthreads();
        // S = Q K^T   (64x64, per-thread 4x4)
        float s[4][4];
        #pragma unroll
        for (int r = 0; r < 4; r++)
            #pragma unroll
            for (int c = 0; c < 4; c++) s[r][c] = 0.f;
        #pragma unroll 8
        for (int d = 0; d < 64; d++) {
            float4 a = *(float4*)&Qs[d][ty * 4];
            float4 b4 = *(float4*)&Ks[d][tx * 4];
            float av[4] = {a.x, a.y, a.z, a.w};
            float bv[4] = {b4.x, b4.y, b4.z, b4.w};
            #pragma unroll
            for (int r = 0; r < 4; r++)
                #pragma unroll
                for (int c = 0; c < 4; c++) s[r][c] += av[r] * bv[c];
        }
        // online softmax (row = ty*4+r, owned by 16 lanes sharing ty)
        #pragma unroll
        for (int r = 0; r < 4; r++) {
            float rm = fmaxf(fmaxf(s[r][0], s[r][1]), fmaxf(s[r][2], s[r][3]));
            rm = fmaxf(rm, __shfl_xor(rm, 1));
            rm = fmaxf(rm, __shfl_xor(rm, 2));
            rm = fmaxf(rm, __shfl_xor(rm, 4));
            rm = fmaxf(rm, __shfl_xor(rm, 8));
            float mn = fmaxf(m[r], rm);
            float corr = __expf(m[r] - mn);
            float p0 = __expf(s[r][0] - mn);
            float p1 = __expf(s[r][1] - mn);
            float p2 = __expf(s[r][2] - mn);
            float p3 = __expf(s[r][3] - mn);
            float rs = p0 + p1 + p2 + p3;
            rs += __shfl_xor(rs, 1);
            rs += __shfl_xor(rs, 2);
            rs += __shfl_xor(rs, 4);
            rs += __shfl_xor(rs, 8);
            l[r] = l[r] * corr + rs;
            m[r] = mn;
            acc[r][0] *= corr; acc[r][1] *= corr; acc[r][2] *= corr; acc[r][3] *= corr;
            s[r][0] = p0; s[r][1] = p1; s[r][2] = p2; s[r][3] = p3;
        }
        // write P transposed [k][r]
        #pragma unroll
        for (int c = 0; c < 4; c++)
            #pragma unroll
            for (int r = 0; r < 4; r++)
                Ps[tx * 4 + c][ty * 4 + r] = s[r][c];
        __syncthreads();
        // O += P V   (per-thread 4x4 over d-cols tx*4..)
        #pragma unroll 8
        for (int k2 = 0; k2 < 64; k2++) {
            float4 a = *(float4*)&Ps[k2][ty * 4];
            float4 b4 = *(float4*)&Vs[k2][tx * 4];
            float av[4] = {a.x, a.y, a.z, a.w};
            float bv[4] = {b4.x, b4.y, b4.z, b4.w};
            #pragma unroll
            for (int r = 0; r < 4; r++)
                #pragma unroll
                for (int c = 0; c < 4; c++) acc[r][c] += av[r] * bv[c];
        }
    }
    // epilogue: O row-major (MROWS x C)
    #pragma unroll
    for (int r = 0; r < 4; r++) {
        float inv = 1.0f / l[r];
        int row = n * T_DIM + qt * 64 + ty * 4 + r;
        float4 o = make_float4(acc[r][0] * inv, acc[r][1] * inv,
                               acc[r][2] * inv, acc[r][3] * inv);
        *(float4*)(Og + (size_t)row * C_DIM + h * HD + tx * 4) = o;
    }
}

// ---------------------------------------------------------------------------
// Kernel 3: output projection + bias + residual.
// Out = O @ Wo + bo + X, row-major (matches d_out layout)
// ---------------------------------------------------------------------------
__global__ __launch_bounds__(256) void out_gemm(
    const float* __restrict__ A, const float* __restrict__ W,
    const float* __restrict__ bias, const float* __restrict__ X,
    float* __restrict__ Out)
{
    __shared__ float As[16][132];
    __shared__ float Bs[16][132];
    const int tid = threadIdx.x;
    const int tx = tid & 15, ty = tid >> 4;
    const int cW = blockIdx.x * 128;
    const int r0 = blockIdx.y * 128;

    float acc[2][2][4][4];
    #pragma unroll
    for (int a = 0; a < 2; a++)
        #pragma unroll
        for (int b = 0; b < 2; b++)
            #pragma unroll
            for (int i = 0; i < 4; i++)
                #pragma unroll
                for (int j = 0; j < 4; j++) acc[a][b][i][j] = 0.f;

    for (int kk = 0; kk < C_DIM; kk += 16) {
        #pragma unroll
        for (int rep = 0; rep < 2; rep++) {
            int flat = rep * 256 + tid;
            int row = flat >> 2, ch = flat & 3;
            float4 v = *(const float4*)(A + (size_t)(r0 + row) * C_DIM + kk + ch * 4);
            As[ch * 4 + 0][row] = v.x;
            As[ch * 4 + 1][row] = v.y;
            As[ch * 4 + 2][row] = v.z;
            As[ch * 4 + 3][row] = v.w;
        }
        #pragma unroll
        for (int rep = 0; rep < 2; rep++) {
            int flat = rep * 256 + tid;
            int row = flat >> 5, ch = flat & 31;
            *(float4*)&Bs[row][ch * 4] =
                *(const float4*)(W + (size_t)(kk + row) * C_DIM + cW + ch * 4);
        }
        __syncthreads();
        #pragma unroll
        for (int k = 0; k < 16; k++) {
            float4 a0 = *(float4*)&As[k][ty * 4];
            float4 a1 = *(float4*)&As[k][64 + ty * 4];
            float4 b0 = *(float4*)&Bs[k][tx * 4];
            float4 b1 = *(float4*)&Bs[k][64 + tx * 4];
            float av[2][4] = {{a0.x, a0.y, a0.z, a0.w}, {a1.x, a1.y, a1.z, a1.w}};
            float bv[2][4] = {{b0.x, b0.y, b0.z, b0.w}, {b1.x, b1.y, b1.z, b1.w}};
            #pragma unroll
            for (int p = 0; p < 2; p++)
                #pragma unroll
                for (int q = 0; q < 4; q++)
                    #pragma unroll
                    for (int u = 0; u < 2; u++)
                        #pragma unroll
                        for (int w = 0; w < 4; w++)
                            acc[p][u][q][w] += av[p][q] * bv[u][w];
        }
        __syncthreads();
    }
    #pragma unroll
    for (int rb = 0; rb < 2; rb++)
        #pragma unroll
        for (int rr = 0; rr < 4; rr++) {
            int r = r0 + rb * 64 + ty * 4 + rr;
            #pragma unroll
            for (int cb = 0; cb < 2; cb++) {
                int c = cW + cb * 64 + tx * 4;
                float4 bv = *(const float4*)(bias + c);
                float4 xv = *(const float4*)(X + (size_t)r * C_DIM + c);
                float4 v = make_float4(acc[rb][cb][rr][0] + bv.x + xv.x,
                                       acc[rb][cb][rr][1] + bv.y + xv.y,
                                       acc[rb][cb][rr][2] + bv.z + xv.z,
                                       acc[rb][cb][rr][3] + bv.w + xv.w);
                *(float4*)(Out + (size_t)r * C_DIM + c) = v;
            }
        }
}

extern "C" void kernel_launch(void* const* d_in, const int* in_sizes, int n_in,
                              void* d_out, int out_size, void* d_ws, size_t ws_size,
                              hipStream_t stream) {
    const float* X  = (const float*)d_in[0];
    const int* idx  = (const int*)d_in[1];
    const float* Wq = (const float*)d_in[2];
    const float* Wk = (const float*)d_in[3];
    const float* Wv = (const float*)d_in[4];
    const float* Wo = (const float*)d_in[5];
    const float* bo = (const float*)d_in[6];
    // d_in[7] = heads (20), hard-coded

    float* ws = (float*)d_ws;
    const size_t SZ = (size_t)MROWS * C_DIM;  // 13,107,200 floats
    float* Q = ws;
    float* K = ws + SZ;
    float* V = ws + 2 * SZ;
    float* O = ws + 3 * SZ;
    // total workspace need: 4*SZ*4 = 209,715,200 bytes

    dim3 g1(30, 80);
    qkv_gemm<<<g1, 256, 0, stream>>>(X, Wq, Wk, Wv, Q, K, V);
    dim3 g2(T_DIM / 64, HEADS, 10);
    flash_attn<<<g2, 256, 0, stream>>>(Q, K, V, idx, O);
    dim3 g3(10, 80);
    out_gemm<<<g3, 256, 0, stream>>>(O, Wo, bo, X, (float*)d_out);
}